// Round 1
// baseline (477.471 us; speedup 1.0000x reference)
//
#include <hip/hip_runtime.h>
#include <math.h>

// Problem constants (x: [2048, 2048, 3, 3] f32, bits=8)
// in_c stride = h*w = 9 floats; group = 8 channels -> 72 consecutive floats
// cells = out_c * (in_c/8) * (h*w) = 2048 * 256 * 9 = 4,718,592
#define HW        9
#define GROUP     8
#define KEEP      4
#define DELTA     127.0f

// ---------------- Kernel 1: global max|x| ----------------
__global__ void maxabs_kernel(const float4* __restrict__ x, unsigned* __restrict__ ws, int n4) {
    float m = 0.0f;
    int stride = gridDim.x * blockDim.x;
    for (int i = blockIdx.x * blockDim.x + threadIdx.x; i < n4; i += stride) {
        float4 v = x[i];
        m = fmaxf(m, fmaxf(fmaxf(fabsf(v.x), fabsf(v.y)),
                           fmaxf(fabsf(v.z), fabsf(v.w))));
    }
    // wave-64 reduction
    #pragma unroll
    for (int off = 32; off > 0; off >>= 1)
        m = fmaxf(m, __shfl_down(m, off, 64));
    if ((threadIdx.x & 63) == 0) {
        // |x| >= 0 so float bit pattern order == uint order
        atomicMax(ws, __float_as_uint(m));
    }
}

// ---------------- Kernel 2: quantize + group top-4 mask ----------------
// One thread per (out_c, group, hw) cell. Reads the 8 group values
// (stride 9 floats apart), computes v_j = rint(tanh(x)/M * 127),
// keeps the 4 largest |v| (ties -> lower channel index), writes v/127 or 0.
__global__ void quant_kernel(const float* __restrict__ x,
                             float* __restrict__ out,
                             const unsigned* __restrict__ ws,
                             int n_cells, int cells_per_o, int groups_per_o) {
    int cell = blockIdx.x * blockDim.x + threadIdx.x;
    if (cell >= n_cells) return;

    // M = max|tanh(x)| = tanh(max|x|)  (tanh odd + monotone; RNE symmetric)
    float maxabs = __uint_as_float(*ws);
    float M = (float)tanh((double)maxabs);

    int o  = cell / cells_per_o;
    int r  = cell - o * cells_per_o;
    int g  = r / HW;
    int hw = r - g * HW;

    size_t base = (size_t)o * (size_t)cells_per_o * GROUP + (size_t)g * (GROUP * HW) + hw;
    const float* p = x + base;
    float*       q = out + base;

    float v[GROUP];
    float a[GROUP];
    #pragma unroll
    for (int j = 0; j < GROUP; ++j) {
        float t = (float)tanh((double)p[j * HW]);  // f32-rounded tanh
        float y = t / M;                            // f32 divide (as reference)
        v[j] = rintf(y * DELTA);                    // numpy round: half-to-even
        a[j] = fabsf(v[j]);
    }

    // rank j = #{ i : |v_i| > |v_j|  or (|v_i| == |v_j| and i < j) }
    // keep iff rank < KEEP  (stable top-k semantics of jax.lax.top_k)
    #pragma unroll
    for (int j = 0; j < GROUP; ++j) {
        int cnt = 0;
        #pragma unroll
        for (int i = 0; i < GROUP; ++i) {
            cnt += (a[i] > a[j]) || (a[i] == a[j] && i < j);
        }
        q[j * HW] = (cnt < KEEP) ? (v[j] / DELTA) : 0.0f;
    }
}

extern "C" void kernel_launch(void* const* d_in, const int* in_sizes, int n_in,
                              void* d_out, int out_size, void* d_ws, size_t ws_size,
                              hipStream_t stream) {
    const float* x = (const float*)d_in[0];
    float* out = (float*)d_out;
    unsigned* ws = (unsigned*)d_ws;

    int n = in_sizes[0];                 // 37,748,736
    int n4 = n / 4;                      // divisible by 4
    int n_cells = n / GROUP;             // 4,718,592
    int cells_per_o = 256 * HW;          // groups_per_o * hw = 2304
    int groups_per_o = 256;              // in_c / GROUP

    hipMemsetAsync(ws, 0, sizeof(unsigned), stream);

    maxabs_kernel<<<1024, 256, 0, stream>>>((const float4*)x, ws, n4);

    int blocks = (n_cells + 255) / 256;
    quant_kernel<<<blocks, 256, 0, stream>>>(x, out, ws, n_cells, cells_per_o, groups_per_o);
}

// Round 2
// 321.187 us; speedup vs baseline: 1.4866x; 1.4866x over previous
//
#include <hip/hip_runtime.h>
#include <math.h>

// Problem constants (x: [2048, 2048, 3, 3] f32, bits=8)
// in_c stride = h*w = 9 floats; group = 8 channels -> 72 consecutive floats
// cells = out_c * (in_c/8) * (h*w) = 2048 * 256 * 9 = 4,718,592
#define HW        9
#define GROUP     8
#define KEEP      4
#define DELTA     127.0f

// ---------------- Kernel 1: global max|x| ----------------
// Block-level reduction -> ONE atomic per block (round-1 version did one
// atomic per wave = 4096 same-address atomics; suspected serialization).
__global__ void maxabs_kernel(const float4* __restrict__ x, unsigned* __restrict__ ws, int n4) {
    __shared__ float red[4];
    float m = 0.0f;
    int stride = gridDim.x * blockDim.x;
    #pragma unroll 4
    for (int i = blockIdx.x * blockDim.x + threadIdx.x; i < n4; i += stride) {
        float4 v = x[i];
        m = fmaxf(m, fmaxf(fmaxf(fabsf(v.x), fabsf(v.y)),
                           fmaxf(fabsf(v.z), fabsf(v.w))));
    }
    // wave-64 butterfly
    #pragma unroll
    for (int off = 32; off > 0; off >>= 1)
        m = fmaxf(m, __shfl_down(m, off, 64));
    int wave = threadIdx.x >> 6;
    if ((threadIdx.x & 63) == 0) red[wave] = m;
    __syncthreads();
    if (threadIdx.x == 0) {
        float b = fmaxf(fmaxf(red[0], red[1]), fmaxf(red[2], red[3]));
        // |x| >= 0 so float bit order == uint order
        atomicMax(ws, __float_as_uint(b));
    }
}

// ---------------- Kernel 2: quantize + group top-4 mask ----------------
// One thread per (out_c, group, hw) cell. v_j = rint(tanh(x)/M * 127);
// keep the 4 largest |v| (ties -> lower channel index; stable top_k).
//
// Fast path: f32 tanhf. The rint decision only differs from the
// reference-precision path when z = tanh(x)/M*127 is within a few ulps of a
// half-integer; detect that and recompute those rare elements with the
// double-precision tanh (identical to the round-1 passing kernel).
__global__ void quant_kernel(const float* __restrict__ x,
                             float* __restrict__ out,
                             const unsigned* __restrict__ ws,
                             int n_cells, int cells_per_o) {
    __shared__ float sM;
    if (threadIdx.x == 0) {
        // M = max|tanh(x)| = tanh(max|x|) (tanh odd+monotone; RNE symmetric)
        sM = (float)tanh((double)__uint_as_float(*ws));
    }
    __syncthreads();
    float M = sM;

    int cell = blockIdx.x * blockDim.x + threadIdx.x;
    if (cell >= n_cells) return;

    int o  = cell / cells_per_o;
    int r  = cell - o * cells_per_o;
    int g  = r / HW;
    int hw = r - g * HW;

    size_t base = (size_t)o * (size_t)cells_per_o * GROUP + (size_t)g * (GROUP * HW) + hw;
    const float* p = x + base;
    float*       q = out + base;

    float v[GROUP];
    float a[GROUP];
    #pragma unroll
    for (int j = 0; j < GROUP; ++j) {
        float xx = p[j * HW];
        float t  = tanhf(xx);               // fast f32 tanh
        float z  = (t / M) * DELTA;         // f32 div + mul, as reference
        float rz = rintf(z);                // numpy round: half-to-even
        float d  = 0.5f - fabsf(z - rz);    // distance from nearest half-integer
        if (d < 4e-6f * fabsf(z) + 2e-6f) {
            // ~32-ulp guard band: recompute with reference-precision tanh
            float td = (float)tanh((double)xx);
            z  = (td / M) * DELTA;
            rz = rintf(z);
        }
        v[j] = rz;
        a[j] = fabsf(rz);
    }

    // rank j = #{ i : |v_i| > |v_j|  or (|v_i| == |v_j| and i < j) }
    // keep iff rank < KEEP (stable top-k semantics of jax.lax.top_k)
    #pragma unroll
    for (int j = 0; j < GROUP; ++j) {
        int cnt = 0;
        #pragma unroll
        for (int i = 0; i < GROUP; ++i) {
            cnt += (a[i] > a[j]) || (a[i] == a[j] && i < j);
        }
        q[j * HW] = (cnt < KEEP) ? (v[j] / DELTA) : 0.0f;
    }
}

extern "C" void kernel_launch(void* const* d_in, const int* in_sizes, int n_in,
                              void* d_out, int out_size, void* d_ws, size_t ws_size,
                              hipStream_t stream) {
    const float* x = (const float*)d_in[0];
    float* out = (float*)d_out;
    unsigned* ws = (unsigned*)d_ws;

    int n = in_sizes[0];                 // 37,748,736
    int n4 = n / 4;                      // divisible by 4
    int n_cells = n / GROUP;             // 4,718,592
    int cells_per_o = 256 * HW;          // 2304

    hipMemsetAsync(ws, 0, sizeof(unsigned), stream);

    maxabs_kernel<<<1024, 256, 0, stream>>>((const float4*)x, ws, n4);

    int blocks = (n_cells + 255) / 256;
    quant_kernel<<<blocks, 256, 0, stream>>>(x, out, ws, n_cells, cells_per_o);
}

// Round 3
// 318.172 us; speedup vs baseline: 1.5007x; 1.0095x over previous
//
#include <hip/hip_runtime.h>
#include <math.h>

// Problem constants (x: [2048, 2048, 3, 3] f32, bits=8)
// in_c stride = h*w = 9 floats; group = 8 channels -> 72 consecutive floats
// cells = out_c * (in_c/8) * (h*w) = 2048 * 256 * 9 = 4,718,592
#define HW        9
#define GROUP     8
#define KEEP      4
#define DELTA     127.0f
#define INV_DELTA (1.0f / 127.0f)

// ---------------- Kernel 1: global max|x| ----------------
__global__ void maxabs_kernel(const float4* __restrict__ x, unsigned* __restrict__ ws, int n4) {
    __shared__ float red[4];
    float m = 0.0f;
    int stride = gridDim.x * blockDim.x;
    for (int i = blockIdx.x * blockDim.x + threadIdx.x; i < n4; i += stride) {
        float4 v = x[i];
        m = fmaxf(m, fmaxf(fmaxf(fabsf(v.x), fabsf(v.y)),
                           fmaxf(fabsf(v.z), fabsf(v.w))));
    }
    #pragma unroll
    for (int off = 32; off > 0; off >>= 1)
        m = fmaxf(m, __shfl_down(m, off, 64));
    int wave = threadIdx.x >> 6;
    if ((threadIdx.x & 63) == 0) red[wave] = m;
    __syncthreads();
    if (threadIdx.x == 0) {
        float b = fmaxf(fmaxf(red[0], red[1]), fmaxf(red[2], red[3]));
        atomicMax(ws, __float_as_uint(b));   // |x|>=0: float bit order == uint order
    }
}

// Branchless fast tanh, rel err <~ 8e-7 (poly for |x|<=0.25, exp form else).
__device__ __forceinline__ float fast_tanh(float x) {
    float ax  = fabsf(x);
    // exp path: t = (E-1)/(E+1), E = e^{2|x|}; clamp to avoid Inf-Inf
    float axc = fminf(ax, 10.0f);
    float E   = __expf(2.0f * axc);            // v_exp_f32-based native exp
    float num = E - 1.0f;
    float den = E + 1.0f;
    float r0  = __builtin_amdgcn_rcpf(den);    // ~1 ulp hw reciprocal
    float r   = r0 * fmaf(-den, r0, 2.0f);     // one Newton step
    float tl  = copysignf(num * r, x);
    // poly path (|x| <= 0.25): tanh = x + x*s*(c1 + s*(c2 + s*(c3 + s*c4)))
    float s = x * x;
    float p = fmaf(s, 0.021869489f, -0.05396825f);   // 62/2835, -17/315
    p = fmaf(s, p, 0.13333334f);                      // 2/15
    p = fmaf(s, p, -0.33333334f);                     // -1/3
    float ts = fmaf(x * s, p, x);
    return (ax <= 0.25f) ? ts : tl;
}

// ---------------- Kernel 2: quantize + group top-4 mask ----------------
// One thread per (out_c, group, hw) cell. v_j = rint(tanh(x)/M * 127);
// keep the 4 largest |v| (ties -> lower channel index; stable top_k).
// Fast path: fast_tanh + single mul by C=127/M. Guard band (>=3x the fast
// path's total error) routes near-half-integer z to the bit-exact
// double-tanh reference chain, so rounding/mask decisions are unchanged.
__global__ void quant_kernel(const float* __restrict__ x,
                             float* __restrict__ out,
                             const unsigned* __restrict__ ws,
                             int n_cells, int cells_per_o) {
    __shared__ float sM, sC;
    if (threadIdx.x == 0) {
        // M = max|tanh(x)| = tanh(max|x|) (tanh odd+monotone; RNE symmetric)
        float mm = (float)tanh((double)__uint_as_float(*ws));
        sM = mm;
        sC = (float)(127.0 / (double)mm);
    }
    __syncthreads();
    float M = sM, C = sC;

    int cell = blockIdx.x * blockDim.x + threadIdx.x;
    if (cell >= n_cells) return;

    int o  = cell / cells_per_o;
    int r  = cell - o * cells_per_o;
    int g  = r / HW;
    int hw = r - g * HW;

    size_t base = (size_t)o * (size_t)cells_per_o * GROUP + (size_t)g * (GROUP * HW) + hw;
    const float* p = x + base;
    float*       q = out + base;

    float v[GROUP];
    float a[GROUP];
    #pragma unroll
    for (int j = 0; j < GROUP; ++j) {
        float xx = p[j * HW];
        float t  = fast_tanh(xx);
        float z  = t * C;
        float rz = rintf(z);                 // numpy round: half-to-even
        float d  = 0.5f - fabsf(z - rz);     // distance from nearest half-int
        if (d < 6e-6f * fabsf(z) + 3e-6f) {
            // guard: recompute with the exact reference-precision chain
            float td = (float)tanh((double)xx);
            float y  = td / M;
            z  = y * DELTA;
            rz = rintf(z);
        }
        v[j] = rz;
        a[j] = fabsf(rz);
    }

    // rank j = #{ i : |v_i| > |v_j|  or (|v_i| == |v_j| and i < j) }
    // keep iff rank < KEEP (stable top-k semantics of jax.lax.top_k)
    #pragma unroll
    for (int j = 0; j < GROUP; ++j) {
        int cnt = 0;
        #pragma unroll
        for (int i = 0; i < GROUP; ++i) {
            cnt += (a[i] > a[j]) || (a[i] == a[j] && i < j);
        }
        q[j * HW] = (cnt < KEEP) ? (v[j] * INV_DELTA) : 0.0f;
    }
}

extern "C" void kernel_launch(void* const* d_in, const int* in_sizes, int n_in,
                              void* d_out, int out_size, void* d_ws, size_t ws_size,
                              hipStream_t stream) {
    const float* x = (const float*)d_in[0];
    float* out = (float*)d_out;
    unsigned* ws = (unsigned*)d_ws;

    int n = in_sizes[0];                 // 37,748,736
    int n4 = n / 4;
    int n_cells = n / GROUP;             // 4,718,592
    int cells_per_o = 256 * HW;          // 2304

    hipMemsetAsync(ws, 0, sizeof(unsigned), stream);

    maxabs_kernel<<<2048, 256, 0, stream>>>((const float4*)x, ws, n4);

    int blocks = (n_cells + 255) / 256;
    quant_kernel<<<blocks, 256, 0, stream>>>(x, out, ws, n_cells, cells_per_o);
}

// Round 4
// 308.291 us; speedup vs baseline: 1.5488x; 1.0321x over previous
//
#include <hip/hip_runtime.h>
#include <math.h>

// Problem constants (x: [2048, 2048, 3, 3] f32, bits=8)
// channel stride = h*w = 9 floats; group-block = 8 channels * 9 = 72
// consecutive floats; n = 37,748,736 = 524,288 group-blocks.
#define HW        9
#define GROUP     8
#define KEEP      4
#define DELTA     127.0f
#define INV_DELTA (1.0f / 127.0f)
#define GB_FLOATS 72

// ---------------- Kernel 1: global max|x| ----------------
__global__ void maxabs_kernel(const float4* __restrict__ x, unsigned* __restrict__ ws, int n4) {
    __shared__ float red[4];
    float m = 0.0f;
    int stride = gridDim.x * blockDim.x;
    #pragma unroll 4
    for (int i = blockIdx.x * blockDim.x + threadIdx.x; i < n4; i += stride) {
        float4 v = x[i];
        m = fmaxf(m, fmaxf(fmaxf(fabsf(v.x), fabsf(v.y)),
                           fmaxf(fabsf(v.z), fabsf(v.w))));
    }
    #pragma unroll
    for (int off = 32; off > 0; off >>= 1)
        m = fmaxf(m, __shfl_down(m, off, 64));
    int wave = threadIdx.x >> 6;
    if ((threadIdx.x & 63) == 0) red[wave] = m;
    __syncthreads();
    if (threadIdx.x == 0) {
        float b = fmaxf(fmaxf(red[0], red[1]), fmaxf(red[2], red[3]));
        atomicMax(ws, __float_as_uint(b));   // |x|>=0: float bit order == uint order
    }
}

// Cold bit-exact reference path (identical to the round-1 passing kernel):
// t = (float)tanh(double x); y = t/M (f32 div); z = y*127; rint.
__device__ __attribute__((noinline)) float ref_rz(float xx, float M) {
    float td = (float)tanh((double)xx);
    float y  = td / M;
    return rintf(y * DELTA);
}

// Fast f32 tanh. Poly (|x|<=0.5): Taylor odd series through x^11,
// rel err <= ~2.5e-7. Exp form else: (E-1)/(E+1) with native exp + NR rcp,
// rel err <= ~1e-6 near the boundary, decaying for larger |x|.
__device__ __forceinline__ float fast_tanh(float x) {
    float ax  = fabsf(x);
    float axc = fminf(ax, 10.0f);
    float E   = __expf(2.0f * axc);
    float num = E - 1.0f;
    float den = E + 1.0f;
    float r0  = __builtin_amdgcn_rcpf(den);
    float r   = r0 * fmaf(-den, r0, 2.0f);      // one Newton step
    float tl  = copysignf(num * r, x);
    float s = x * x;
    float p = fmaf(s, 0.0035921280f, -0.0088632358f);  // 21844/6081075, -1382/155925
    p = fmaf(s, p, 0.021869488f);                       // 62/2835
    p = fmaf(s, p, -0.053968254f);                      // -17/315
    p = fmaf(s, p, 0.13333334f);                        // 2/15
    p = fmaf(s, p, -0.33333334f);                       // -1/3
    float ts = fmaf(x * s, p, x);
    return (ax <= 0.5f) ? ts : tl;
}

// ---------------- Kernel 2: quantize + group top-4 mask ----------------
// One thread per group-block (72 contiguous floats = 8 channels x 9 hw).
// 18 float4 loads -> registers -> 9 cells of (quantize + stable-top-4 mask)
// -> results written in place -> 18 float4 stores.
__global__ void quant_kernel(const float4* __restrict__ x,
                             float4* __restrict__ out,
                             const unsigned* __restrict__ ws,
                             int n_gb) {
    __shared__ float sM, sC;
    if (threadIdx.x == 0) {
        // M = max|tanh(x)| = tanh(max|x|) (tanh odd+monotone; RNE symmetric)
        float mm = (float)tanh((double)__uint_as_float(*ws));
        sM = mm;
        sC = (float)(127.0 / (double)mm);
    }
    __syncthreads();
    float M = sM, C = sC;

    int gb = blockIdx.x * blockDim.x + threadIdx.x;
    if (gb >= n_gb) return;

    const float4* p = x   + (size_t)gb * (GB_FLOATS / 4);
    float4*       q = out + (size_t)gb * (GB_FLOATS / 4);

    float f[GB_FLOATS];
    #pragma unroll
    for (int k = 0; k < GB_FLOATS / 4; ++k) {
        float4 v = p[k];
        f[4 * k + 0] = v.x; f[4 * k + 1] = v.y;
        f[4 * k + 2] = v.z; f[4 * k + 3] = v.w;
    }

    #pragma unroll
    for (int hw = 0; hw < HW; ++hw) {
        float v8[GROUP], a8[GROUP];
        #pragma unroll
        for (int j = 0; j < GROUP; ++j) {
            float xx = f[j * HW + hw];
            float t  = fast_tanh(xx);
            float z  = t * C;
            float rz = rintf(z);                 // numpy round: half-to-even
            float d  = 0.5f - fabsf(z - rz);     // distance to nearest half-int
            if (d < fmaf(2e-6f, fabsf(z), 5e-7f))
                rz = ref_rz(xx, M);              // cold, bit-exact chain
            v8[j] = rz;
            a8[j] = fabsf(rz);
        }
        // stable top-4: rank[j] = #{i beating j}; i<j beats iff a_i >= a_j
        int rank[GROUP] = {0, 0, 0, 0, 0, 0, 0, 0};
        #pragma unroll
        for (int i = 0; i < GROUP; ++i) {
            #pragma unroll
            for (int j = i + 1; j < GROUP; ++j) {
                bool ge = (a8[i] >= a8[j]);
                rank[j] += ge ? 1 : 0;
                rank[i] += ge ? 0 : 1;
            }
        }
        #pragma unroll
        for (int j = 0; j < GROUP; ++j) {
            f[j * HW + hw] = (rank[j] < KEEP) ? (v8[j] * INV_DELTA) : 0.0f;
        }
    }

    #pragma unroll
    for (int k = 0; k < GB_FLOATS / 4; ++k) {
        float4 v;
        v.x = f[4 * k + 0]; v.y = f[4 * k + 1];
        v.z = f[4 * k + 2]; v.w = f[4 * k + 3];
        q[k] = v;
    }
}

extern "C" void kernel_launch(void* const* d_in, const int* in_sizes, int n_in,
                              void* d_out, int out_size, void* d_ws, size_t ws_size,
                              hipStream_t stream) {
    const float* x = (const float*)d_in[0];
    float* out = (float*)d_out;
    unsigned* ws = (unsigned*)d_ws;

    int n = in_sizes[0];                 // 37,748,736
    int n4 = n / 4;
    int n_gb = n / GB_FLOATS;            // 524,288

    hipMemsetAsync(ws, 0, sizeof(unsigned), stream);

    maxabs_kernel<<<2048, 256, 0, stream>>>((const float4*)x, ws, n4);

    int blocks = (n_gb + 255) / 256;     // 2048
    quant_kernel<<<blocks, 256, 0, stream>>>((const float4*)x, (float4*)out, ws, n_gb);
}